// Round 7
// baseline (230.572 us; speedup 1.0000x reference)
//
#include <hip/hip_runtime.h>
#include <hip/hip_bf16.h>

typedef __attribute__((ext_vector_type(8))) short short8;
typedef __attribute__((ext_vector_type(4))) float f32x4;

static constexpr int N = 4096;
static constexpr int D = 1024;
#define TEMP_INV 20.0f
#define LOG2E_X20 28.8539008178f   // 20 * log2(e); exp(20x) == exp2(x * this)

#define GLD_LDS16(gp, lp) __builtin_amdgcn_global_load_lds(                      \
    (const __attribute__((address_space(1))) void*)(gp),                         \
    (__attribute__((address_space(3))) void*)(lp), 16, 0, 0)

// ---------------------------------------------------------------------------
// Kernel 1: row-normalize c and ch -> bf16 workspace; zero the loss slot.
// ---------------------------------------------------------------------------
__global__ __launch_bounds__(256) void normalize_k(
    const float* __restrict__ c, const float* __restrict__ ch,
    unsigned short* __restrict__ cnb, unsigned short* __restrict__ chnb,
    float* __restrict__ loss_slot) {
  const int r = blockIdx.x;   // 0..2N-1
  const int t = threadIdx.x;  // 0..255
  if (r == 0 && t == 0) *loss_slot = 0.0f;

  const float* src = (r < N) ? (c + (size_t)r * D) : (ch + (size_t)(r - N) * D);
  unsigned short* dst = (r < N) ? (cnb + (size_t)r * D) : (chnb + (size_t)(r - N) * D);

  float4 v = ((const float4*)src)[t];
  float ss = v.x * v.x + v.y * v.y + v.z * v.z + v.w * v.w;
  #pragma unroll
  for (int off = 32; off > 0; off >>= 1) ss += __shfl_xor(ss, off);
  __shared__ float red[4];
  if ((t & 63) == 0) red[t >> 6] = ss;
  __syncthreads();
  float tot = red[0] + red[1] + red[2] + red[3];
  float sc = 1.0f / fmaxf(sqrtf(tot), 1e-8f);

  __hip_bfloat16 b0 = __float2bfloat16(v.x * sc);
  __hip_bfloat16 b1 = __float2bfloat16(v.y * sc);
  __hip_bfloat16 b2 = __float2bfloat16(v.z * sc);
  __hip_bfloat16 b3 = __float2bfloat16(v.w * sc);
  ushort4 o;
  o.x = *(unsigned short*)&b0;
  o.y = *(unsigned short*)&b1;
  o.z = *(unsigned short*)&b2;
  o.w = *(unsigned short*)&b3;
  ((ushort4*)dst)[t] = o;
}

// ---------------------------------------------------------------------------
// Kernel 2: y_true[i][j] = (label_i == label_j).
// yt = out + N*N + 1 is only 4-byte aligned -> scalar dword stores only.
// Each wave store covers 256 contiguous bytes, so coalescing matches float4.
// ---------------------------------------------------------------------------
__global__ __launch_bounds__(256) void ytrue_k(
    const int* __restrict__ lbl, float* __restrict__ yt) {
  const size_t base = (size_t)blockIdx.x * 1024;
  const int row = (int)(base >> 12);           // 4096 elements per row
  const int lr = lbl[row];
  #pragma unroll
  for (int q = 0; q < 4; ++q) {
    const size_t e = base + q * 256 + threadIdx.x;
    const int col = (int)(e & 4095);
    yt[e] = (lbl[col] == lr) ? 1.0f : 0.0f;
  }
}

// ---------------------------------------------------------------------------
// Kernel 3: NT bf16 MFMA GEMM, 128x128 tile, BK=32, 4 waves (2x2 of 64x64),
// 2-phase double-buffered LDS (T3-minimum): issue next chunk's
// global_load_lds BEFORE compute of current; ONE barrier per K-step.
// Writes sim and per-wave per-row loss partials:
//   part[row][tile] = { s = sum_cols exp(20*v),  p = sum_cols mask*v }
// tile = bn*2 + wn. No max subtraction needed: |v|<=1 (cosine).
// ---------------------------------------------------------------------------
__global__ __launch_bounds__(256) void gemm_k(
    const unsigned short* __restrict__ A,  // cn  bf16 [N][D]
    const unsigned short* __restrict__ B,  // chn bf16 [N][D]
    const int* __restrict__ lbl,
    float* __restrict__ sim, float* __restrict__ part) {
  __shared__ __align__(16) unsigned short Als[2][128 * 32];  // 16 KB x2
  __shared__ __align__(16) unsigned short Bls[2][128 * 32];

  const int t = threadIdx.x;
  const int w = t >> 6, l = t & 63;
  const int bm = blockIdx.y, bn = blockIdx.x;
  const int wm = w >> 1, wn = w & 1;

  f32x4 acc[4][4] = {};

  // staging: chunk idx = w*64 + l covers bytes [idx*16, idx*16+16) of the
  // 8 KB half; row = idx>>2 (64 B/row), col elem = (idx&3)*8.
  const unsigned short* ga0 = A + (size_t)(bm * 128 + (t >> 2)) * D + (t & 3) * 8;
  const unsigned short* gb0 = B + (size_t)(bn * 128 + (t >> 2)) * D + (t & 3) * 8;

  const int frow = (l & 15);
  const int fk = (l >> 4) * 8;

  // stage K-chunk k0 (elements [k0*32, k0*32+32)) into buffer bb
#define STAGE(bb, kc) do {                                                     \
    const int _k = (kc) * 32;                                                  \
    GLD_LDS16(ga0 + _k, &Als[bb][w * 512]);                                    \
    GLD_LDS16(ga0 + 64 * D + _k, &Als[bb][2048 + w * 512]);                    \
    GLD_LDS16(gb0 + _k, &Bls[bb][w * 512]);                                    \
    GLD_LDS16(gb0 + 64 * D + _k, &Bls[bb][2048 + w * 512]);                    \
  } while (0)

#define COMPUTE(bb) do {                                                       \
    short8 af[4], bf[4];                                                       \
    _Pragma("unroll")                                                          \
    for (int m = 0; m < 4; ++m)                                                \
      af[m] = *(const short8*)&Als[bb][(wm * 64 + m * 16 + frow) * 32 + fk];   \
    _Pragma("unroll")                                                          \
    for (int n = 0; n < 4; ++n)                                                \
      bf[n] = *(const short8*)&Bls[bb][(wn * 64 + n * 16 + frow) * 32 + fk];   \
    _Pragma("unroll")                                                          \
    for (int m = 0; m < 4; ++m)                                                \
      _Pragma("unroll")                                                        \
      for (int n = 0; n < 4; ++n)                                              \
        acc[m][n] = __builtin_amdgcn_mfma_f32_16x16x32_bf16(af[m], bf[n],      \
                                                            acc[m][n], 0, 0, 0);\
  } while (0)

  // prologue: chunk 0 -> buf0
  STAGE(0, 0);
  __syncthreads();  // compiler drains vmcnt before s_barrier

  // main loop: chunks 0..29 computed, chunks 1..30 prefetched (D/32 = 32)
  for (int kk = 0; kk < 15; ++kk) {
    STAGE(1, 2 * kk + 1);   // prefetch odd chunk while computing even
    COMPUTE(0);
    __syncthreads();        // drains vmcnt (stage done) + sync readers
    STAGE(0, 2 * kk + 2);
    COMPUTE(1);
    __syncthreads();
  }
  // tail: chunk 30 in buf0, prefetch 31, compute both
  STAGE(1, 31);
  COMPUTE(0);
  __syncthreads();
  COMPUTE(1);
#undef STAGE
#undef COMPUTE

  // Epilogue. C/D mapping: col = lane&15, row = (lane>>4)*4 + reg.
  // For fixed (m,r): 16 lanes sharing (l>>4) hold the same output row,
  // cols col0 + n*16 + (l&15) -> shfl_xor {1,2,4,8} row-reduces.
  const int row0 = bm * 128 + wm * 64;
  const int col0 = bn * 128 + wn * 64;
  const int tile = bn * 2 + wn;
  int lc[4];
  #pragma unroll
  for (int n = 0; n < 4; ++n) lc[n] = lbl[col0 + n * 16 + (l & 15)];

  #pragma unroll
  for (int m = 0; m < 4; ++m) {
    #pragma unroll
    for (int r = 0; r < 4; ++r) {
      const int grow = row0 + m * 16 + (l >> 4) * 4 + r;
      const int lr = lbl[grow];
      const size_t base = (size_t)grow * N + col0 + (l & 15);
      float s = 0.0f, p = 0.0f;
      #pragma unroll
      for (int n = 0; n < 4; ++n) {
        const float v = acc[m][n][r];
        sim[base + n * 16] = v;
        s += exp2f(v * LOG2E_X20);
        p += (lc[n] == lr) ? v : 0.0f;
      }
      #pragma unroll
      for (int off = 1; off < 16; off <<= 1) {
        s += __shfl_xor(s, off);
        p += __shfl_xor(p, off);
      }
      if ((l & 15) == 0) {
        float* pp = &part[(size_t)grow * 128 + tile * 2];
        pp[0] = s;
        pp[1] = p;
      }
    }
  }
}

// ---------------------------------------------------------------------------
// Kernel 4: finalize. 16 blocks x 256 thr; thread t of block b owns row i.
// cnt from a label histogram; sexp/psum from 64 tile partials.
// row_val = 20*psum/cnt - log(sexp); loss = mean(-row_val).
// ---------------------------------------------------------------------------
__global__ __launch_bounds__(256) void finalize_k(
    const float* __restrict__ part, const int* __restrict__ lbl,
    float* loss_slot) {
  __shared__ int hist[64];
  __shared__ float redl[4];
  const int t = threadIdx.x;
  const int i = blockIdx.x * 256 + t;

  if (t < 64) hist[t] = 0;
  __syncthreads();
  for (int j = t; j < N; j += 256) atomicAdd(&hist[lbl[j] & 63], 1);
  __syncthreads();

  const float* pr = part + (size_t)i * 128;
  float sexp = 0.0f, psum = 0.0f;
  #pragma unroll
  for (int tt = 0; tt < 64; ++tt) {
    sexp += pr[tt * 2];
    psum += pr[tt * 2 + 1];
  }
  const float cnt = (float)hist[lbl[i] & 63];
  const float row = TEMP_INV * psum / cnt - logf(sexp);
  float contrib = -row * (1.0f / (float)N);

  #pragma unroll
  for (int off = 32; off > 0; off >>= 1) contrib += __shfl_xor(contrib, off);
  if ((t & 63) == 0) redl[t >> 6] = contrib;
  __syncthreads();
  if (t == 0) atomicAdd(loss_slot, redl[0] + redl[1] + redl[2] + redl[3]);
}

// ---------------------------------------------------------------------------
extern "C" void kernel_launch(void* const* d_in, const int* in_sizes, int n_in,
                              void* d_out, int out_size, void* d_ws, size_t ws_size,
                              hipStream_t stream) {
  const float* c  = (const float*)d_in[0];
  const float* ch = (const float*)d_in[1];
  const int* lbl  = (const int*)d_in[2];

  float* out = (float*)d_out;
  float* sim = out;                            // [N*N]
  float* loss_slot = out + (size_t)N * N;      // [1]
  float* ytrue = out + (size_t)N * N + 1;      // [N*N] (only 4B-aligned!)

  unsigned short* cnb  = (unsigned short*)d_ws;            // bf16 cn  [N][D]
  unsigned short* chnb = cnb + (size_t)N * D;              // bf16 chn [N][D]
  float* part = (float*)(chnb + (size_t)N * D);            // [N][64][2] = 2 MB

  normalize_k<<<2 * N, 256, 0, stream>>>(c, ch, cnb, chnb, loss_slot);
  ytrue_k<<<N * N / 1024, 256, 0, stream>>>(lbl, ytrue);
  dim3 g(N / 128, N / 128);
  gemm_k<<<g, 256, 0, stream>>>(cnb, chnb, lbl, sim, part);
  finalize_k<<<N / 256, 256, 0, stream>>>(part, lbl, loss_slot);
}

// Round 9
// 217.146 us; speedup vs baseline: 1.0618x; 1.0618x over previous
//
#include <hip/hip_runtime.h>
#include <hip/hip_bf16.h>

typedef __attribute__((ext_vector_type(8))) short short8;
typedef __attribute__((ext_vector_type(4))) float f32x4;

static constexpr int N = 4096;
static constexpr int D = 1024;
#define TEMP_INV 20.0f
#define LOG2E_X20 28.8539008178f   // 20 * log2(e); exp(20x) == exp2(x * this)

#define GLD_LDS16(gp, lp) __builtin_amdgcn_global_load_lds(                      \
    (const __attribute__((address_space(1))) void*)(gp),                         \
    (__attribute__((address_space(3))) void*)(lp), 16, 0, 0)

// ---------------------------------------------------------------------------
// Kernel 1: row-normalize c and ch -> bf16 workspace; zero the loss slot.
// ---------------------------------------------------------------------------
__global__ __launch_bounds__(256) void normalize_k(
    const float* __restrict__ c, const float* __restrict__ ch,
    unsigned short* __restrict__ cnb, unsigned short* __restrict__ chnb,
    float* __restrict__ loss_slot) {
  const int r = blockIdx.x;   // 0..2N-1
  const int t = threadIdx.x;  // 0..255
  if (r == 0 && t == 0) *loss_slot = 0.0f;

  const float* src = (r < N) ? (c + (size_t)r * D) : (ch + (size_t)(r - N) * D);
  unsigned short* dst = (r < N) ? (cnb + (size_t)r * D) : (chnb + (size_t)(r - N) * D);

  float4 v = ((const float4*)src)[t];
  float ss = v.x * v.x + v.y * v.y + v.z * v.z + v.w * v.w;
  #pragma unroll
  for (int off = 32; off > 0; off >>= 1) ss += __shfl_xor(ss, off);
  __shared__ float red[4];
  if ((t & 63) == 0) red[t >> 6] = ss;
  __syncthreads();
  float tot = red[0] + red[1] + red[2] + red[3];
  float sc = 1.0f / fmaxf(sqrtf(tot), 1e-8f);

  __hip_bfloat16 b0 = __float2bfloat16(v.x * sc);
  __hip_bfloat16 b1 = __float2bfloat16(v.y * sc);
  __hip_bfloat16 b2 = __float2bfloat16(v.z * sc);
  __hip_bfloat16 b3 = __float2bfloat16(v.w * sc);
  ushort4 o;
  o.x = *(unsigned short*)&b0;
  o.y = *(unsigned short*)&b1;
  o.z = *(unsigned short*)&b2;
  o.w = *(unsigned short*)&b3;
  ((ushort4*)dst)[t] = o;
}

// ---------------------------------------------------------------------------
// Kernel 2: y_true[i][j] = (label_i == label_j).
// yt = out + N*N + 1 is only 4-byte aligned -> scalar dword stores only.
// Each wave store covers 256 contiguous bytes, so coalescing matches float4.
// ---------------------------------------------------------------------------
__global__ __launch_bounds__(256) void ytrue_k(
    const int* __restrict__ lbl, float* __restrict__ yt) {
  const size_t base = (size_t)blockIdx.x * 1024;
  const int row = (int)(base >> 12);           // 4096 elements per row
  const int lr = lbl[row];
  #pragma unroll
  for (int q = 0; q < 4; ++q) {
    const size_t e = base + q * 256 + threadIdx.x;
    const int col = (int)(e & 4095);
    yt[e] = (lbl[col] == lr) ? 1.0f : 0.0f;
  }
}

// ---------------------------------------------------------------------------
// Kernel 3: NT bf16 MFMA GEMM, 256x256 tile, BK=64, 8 waves (2M x 4N,
// per-wave 128x64 output, acc[8][4]), 512 threads, 2-phase dbuf LDS (128 KB,
// 1 block/CU). Same sync skeleton as the verified 128^2 kernel — parameter
// scale-up only. Writes sim and per-wave per-row loss partials:
//   part[row][tile] = { s = sum_cols exp(20*v), p = sum_cols mask*v },
// tile = bn*4 + wn (64 col-chunks of 64). No max subtraction: |v|<=1.
// ---------------------------------------------------------------------------
__global__ __launch_bounds__(512) void gemm_k(
    const unsigned short* __restrict__ A,  // cn  bf16 [N][D]
    const unsigned short* __restrict__ B,  // chn bf16 [N][D]
    const int* __restrict__ lbl,
    float* __restrict__ sim, float* __restrict__ part) {
  __shared__ __align__(16) unsigned short Als[2][256 * 64];  // 32 KB x2
  __shared__ __align__(16) unsigned short Bls[2][256 * 64];  // 32 KB x2

  const int t = threadIdx.x;             // 0..511
  const int w = t >> 6, l = t & 63;      // 8 waves
  const int bm = blockIdx.y, bn = blockIdx.x;
  const int wm = w >> 2, wn = w & 3;     // 2M x 4N

  f32x4 acc[8][4] = {};

  // staging: per operand 256x64 bf16 = 32 KB = 2048 chunks of 16 B.
  // chunk c = q*512 + t (q=0..3): row = c>>3 = q*64 + (t>>3),
  // col elem = (c&7)*8 = (t&7)*8. LDS elem base (wave-uniform per (w,q)):
  // c*8 = q*4096 + w*512 (+ lane*8 added by HW).
  const unsigned short* ga0 = A + (size_t)(bm * 256 + (t >> 3)) * D + (t & 7) * 8;
  const unsigned short* gb0 = B + (size_t)(bn * 256 + (t >> 3)) * D + (t & 7) * 8;

  const int frow = (l & 15);
  const int fk = (l >> 4) * 8;

  // stage K-chunk ks (elements [ks*64, ks*64+64)) into buffer bb
#define STAGE(bb, ks) do {                                                     \
    const int _k = (ks) * 64;                                                  \
    _Pragma("unroll")                                                          \
    for (int q = 0; q < 4; ++q) {                                              \
      GLD_LDS16(ga0 + (size_t)q * 64 * D + _k, &Als[bb][q * 4096 + w * 512]);  \
      GLD_LDS16(gb0 + (size_t)q * 64 * D + _k, &Bls[bb][q * 4096 + w * 512]);  \
    }                                                                          \
  } while (0)

  // fragment read: row = wm*128 + m*16 + frow (A) / wn*64 + n*16 + frow (B),
  // elem = row*64 + ksub*32 + fk
#define COMPUTE(bb) do {                                                       \
    _Pragma("unroll")                                                          \
    for (int ksub = 0; ksub < 2; ++ksub) {                                     \
      short8 af[8], bf[4];                                                     \
      _Pragma("unroll")                                                        \
      for (int m = 0; m < 8; ++m)                                              \
        af[m] = *(const short8*)&Als[bb][(wm * 128 + m * 16 + frow) * 64 +     \
                                         ksub * 32 + fk];                      \
      _Pragma("unroll")                                                        \
      for (int n = 0; n < 4; ++n)                                              \
        bf[n] = *(const short8*)&Bls[bb][(wn * 64 + n * 16 + frow) * 64 +      \
                                         ksub * 32 + fk];                      \
      _Pragma("unroll")                                                        \
      for (int m = 0; m < 8; ++m)                                              \
        _Pragma("unroll")                                                      \
        for (int n = 0; n < 4; ++n)                                            \
          acc[m][n] = __builtin_amdgcn_mfma_f32_16x16x32_bf16(af[m], bf[n],    \
                                                          acc[m][n], 0, 0, 0); \
    }                                                                          \
  } while (0)

  // prologue: chunk 0 -> buf0  (D/64 = 16 K-chunks total)
  STAGE(0, 0);
  __syncthreads();

  for (int kk = 0; kk < 7; ++kk) {
    STAGE(1, 2 * kk + 1);
    COMPUTE(0);
    __syncthreads();
    STAGE(0, 2 * kk + 2);
    COMPUTE(1);
    __syncthreads();
  }
  // tail: chunk 14 in buf0; prefetch 15; compute both
  STAGE(1, 15);
  COMPUTE(0);
  __syncthreads();
  COMPUTE(1);
#undef STAGE
#undef COMPUTE

  // Epilogue. C/D mapping: col = lane&15, row = (lane>>4)*4 + reg.
  // For fixed (m,r): 16 lanes sharing (l>>4) hold the same output row,
  // cols col0 + n*16 + (l&15) -> shfl_xor {1,2,4,8} row-reduces.
  const int row0 = bm * 256 + wm * 128;
  const int col0 = bn * 256 + wn * 64;
  const int tile = bn * 4 + wn;          // 16 blocks x 4 = 64 tiles of 64 cols
  int lc[4];
  #pragma unroll
  for (int n = 0; n < 4; ++n) lc[n] = lbl[col0 + n * 16 + (l & 15)];

  #pragma unroll
  for (int m = 0; m < 8; ++m) {
    #pragma unroll
    for (int r = 0; r < 4; ++r) {
      const int grow = row0 + m * 16 + (l >> 4) * 4 + r;
      const int lr = lbl[grow];
      const size_t base = (size_t)grow * N + col0 + (l & 15);
      float s = 0.0f, p = 0.0f;
      #pragma unroll
      for (int n = 0; n < 4; ++n) {
        const float v = acc[m][n][r];
        sim[base + n * 16] = v;
        s += exp2f(v * LOG2E_X20);
        p += (lc[n] == lr) ? v : 0.0f;
      }
      #pragma unroll
      for (int off = 1; off < 16; off <<= 1) {
        s += __shfl_xor(s, off);
        p += __shfl_xor(p, off);
      }
      if ((l & 15) == 0) {
        float* pp = &part[(size_t)grow * 128 + tile * 2];
        pp[0] = s;
        pp[1] = p;
      }
    }
  }
}

// ---------------------------------------------------------------------------
// Kernel 4: finalize. 16 blocks x 256 thr; thread t of block b owns row i.
// cnt from a label histogram; sexp/psum from 64 tile partials.
// row_val = 20*psum/cnt - log(sexp); loss = mean(-row_val).
// ---------------------------------------------------------------------------
__global__ __launch_bounds__(256) void finalize_k(
    const float* __restrict__ part, const int* __restrict__ lbl,
    float* loss_slot) {
  __shared__ int hist[64];
  __shared__ float redl[4];
  const int t = threadIdx.x;
  const int i = blockIdx.x * 256 + t;

  if (t < 64) hist[t] = 0;
  __syncthreads();
  for (int j = t; j < N; j += 256) atomicAdd(&hist[lbl[j] & 63], 1);
  __syncthreads();

  const float* pr = part + (size_t)i * 128;
  float sexp = 0.0f, psum = 0.0f;
  #pragma unroll
  for (int tt = 0; tt < 64; ++tt) {
    sexp += pr[tt * 2];
    psum += pr[tt * 2 + 1];
  }
  const float cnt = (float)hist[lbl[i] & 63];
  const float row = TEMP_INV * psum / cnt - logf(sexp);
  float contrib = -row * (1.0f / (float)N);

  #pragma unroll
  for (int off = 32; off > 0; off >>= 1) contrib += __shfl_xor(contrib, off);
  if ((t & 63) == 0) redl[t >> 6] = contrib;
  __syncthreads();
  if (t == 0) atomicAdd(loss_slot, redl[0] + redl[1] + redl[2] + redl[3]);
}

// ---------------------------------------------------------------------------
extern "C" void kernel_launch(void* const* d_in, const int* in_sizes, int n_in,
                              void* d_out, int out_size, void* d_ws, size_t ws_size,
                              hipStream_t stream) {
  const float* c  = (const float*)d_in[0];
  const float* ch = (const float*)d_in[1];
  const int* lbl  = (const int*)d_in[2];

  float* out = (float*)d_out;
  float* sim = out;                            // [N*N]
  float* loss_slot = out + (size_t)N * N;      // [1]
  float* ytrue = out + (size_t)N * N + 1;      // [N*N] (only 4B-aligned!)

  unsigned short* cnb  = (unsigned short*)d_ws;            // bf16 cn  [N][D]
  unsigned short* chnb = cnb + (size_t)N * D;              // bf16 chn [N][D]
  float* part = (float*)(chnb + (size_t)N * D);            // [N][64][2] = 2 MB

  normalize_k<<<2 * N, 256, 0, stream>>>(c, ch, cnb, chnb, loss_slot);
  ytrue_k<<<N * N / 1024, 256, 0, stream>>>(lbl, ytrue);
  dim3 g(N / 256, N / 256);
  gemm_k<<<g, 512, 0, stream>>>(cnb, chnb, lbl, sim, part);
  finalize_k<<<N / 256, 256, 0, stream>>>(part, lbl, loss_slot);
}

// Round 10
// 214.006 us; speedup vs baseline: 1.0774x; 1.0147x over previous
//
#include <hip/hip_runtime.h>
#include <hip/hip_bf16.h>

typedef __attribute__((ext_vector_type(8))) short short8;
typedef __attribute__((ext_vector_type(4))) float f32x4;

static constexpr int N = 4096;
static constexpr int D = 1024;
#define TEMP_INV 20.0f
#define LOG2E_X20 28.8539008178f   // 20 * log2(e); exp(20x) == exp2(x * this)

#define GLD_LDS16(gp, lp) __builtin_amdgcn_global_load_lds(                      \
    (const __attribute__((address_space(1))) void*)(gp),                         \
    (__attribute__((address_space(3))) void*)(lp), 16, 0, 0)

// ---------------------------------------------------------------------------
// Kernel 1: row-normalize c and ch -> bf16 workspace; zero the loss slot.
// ---------------------------------------------------------------------------
__global__ __launch_bounds__(256) void normalize_k(
    const float* __restrict__ c, const float* __restrict__ ch,
    unsigned short* __restrict__ cnb, unsigned short* __restrict__ chnb,
    float* __restrict__ loss_slot) {
  const int r = blockIdx.x;   // 0..2N-1
  const int t = threadIdx.x;  // 0..255
  if (r == 0 && t == 0) *loss_slot = 0.0f;

  const float* src = (r < N) ? (c + (size_t)r * D) : (ch + (size_t)(r - N) * D);
  unsigned short* dst = (r < N) ? (cnb + (size_t)r * D) : (chnb + (size_t)(r - N) * D);

  float4 v = ((const float4*)src)[t];
  float ss = v.x * v.x + v.y * v.y + v.z * v.z + v.w * v.w;
  #pragma unroll
  for (int off = 32; off > 0; off >>= 1) ss += __shfl_xor(ss, off);
  __shared__ float red[4];
  if ((t & 63) == 0) red[t >> 6] = ss;
  __syncthreads();
  float tot = red[0] + red[1] + red[2] + red[3];
  float sc = 1.0f / fmaxf(sqrtf(tot), 1e-8f);

  __hip_bfloat16 b0 = __float2bfloat16(v.x * sc);
  __hip_bfloat16 b1 = __float2bfloat16(v.y * sc);
  __hip_bfloat16 b2 = __float2bfloat16(v.z * sc);
  __hip_bfloat16 b3 = __float2bfloat16(v.w * sc);
  ushort4 o;
  o.x = *(unsigned short*)&b0;
  o.y = *(unsigned short*)&b1;
  o.z = *(unsigned short*)&b2;
  o.w = *(unsigned short*)&b3;
  ((ushort4*)dst)[t] = o;
}

// ---------------------------------------------------------------------------
// Kernel 2: y_true[i][j] = (label_i == label_j).
// yt = out + N*N + 1 is only 4-byte aligned -> scalar dword stores only.
// ---------------------------------------------------------------------------
__global__ __launch_bounds__(256) void ytrue_k(
    const int* __restrict__ lbl, float* __restrict__ yt) {
  const size_t base = (size_t)blockIdx.x * 1024;
  const int row = (int)(base >> 12);
  const int lr = lbl[row];
  #pragma unroll
  for (int q = 0; q < 4; ++q) {
    const size_t e = base + q * 256 + threadIdx.x;
    const int col = (int)(e & 4095);
    yt[e] = (lbl[col] == lr) ? 1.0f : 0.0f;
  }
}

// ---------------------------------------------------------------------------
// Kernel 3: NT bf16 MFMA GEMM, 256x256 tile, BK=32, 8 waves (2M x 4N),
// TRIPLE-buffered LDS (3 x 32 KB), stage-2-ahead, counted vmcnt (never 0
// mid-loop), raw s_barrier. T2 swizzle: 16B-slot involution
// slot ^= (row>>1)&3, applied on the GLOBAL SOURCE address (LDS dest linear,
// required by global_load_lds) and on the ds_read col. T5 setprio on MFMA.
// Writes sim and per-wave per-row loss partials:
//   part[row][tile] = { s = sum_cols exp(20*v), p = sum_cols mask*v },
// tile = bn*4 + wn (64 col-chunks of 64). No max subtraction: |v|<=1.
// ---------------------------------------------------------------------------
__global__ __launch_bounds__(512) void gemm_k(
    const unsigned short* __restrict__ A,  // cn  bf16 [N][D]
    const unsigned short* __restrict__ B,  // chn bf16 [N][D]
    const int* __restrict__ lbl,
    float* __restrict__ sim, float* __restrict__ part) {
  __shared__ __align__(16) unsigned short Als[3][256 * 32];  // 16 KB x3
  __shared__ __align__(16) unsigned short Bls[3][256 * 32];  // 16 KB x3

  const int t = threadIdx.x;             // 0..511
  const int w = t >> 6, l = t & 63;      // 8 waves
  const int bm = blockIdx.y, bn = blockIdx.x;
  const int wm = w >> 2, wn = w & 3;     // 2M x 4N

  f32x4 acc[8][4] = {};

  // staging (per op, per stage): 256x32 bf16 = 16 KB = 1024 chunks of 16 B,
  // 2 chunks/thread (q=0,1). chunk c = q*512 + t: row = q*128 + (t>>2),
  // slot = t&3. Source slot pre-swizzled: slot ^ ((row>>1)&3) = (t&3)^((t>>3)&3).
  // LDS dest linear: elem c*8 = q*4096 + w*512 (+ lane*8 by HW).
  const int srow = t >> 2;
  const int sslot = (t & 3) ^ ((t >> 3) & 3);
  const unsigned short* gaS = A + (size_t)(bm * 256 + srow) * D + sslot * 8;
  const unsigned short* gbS = B + (size_t)(bn * 256 + srow) * D + sslot * 8;

  const int frow = (l & 15);
  const int fk = (l >> 4) * 8;
  const int rswz = ((frow >> 1) & 3) << 3;   // read-side swizzle (elems)

#define STAGE(bb, ks) do {                                                     \
    const int _k = (ks) * 32;                                                  \
    GLD_LDS16(gaS + _k, &Als[bb][w * 512]);                                    \
    GLD_LDS16(gaS + (size_t)128 * D + _k, &Als[bb][4096 + w * 512]);           \
    GLD_LDS16(gbS + _k, &Bls[bb][w * 512]);                                    \
    GLD_LDS16(gbS + (size_t)128 * D + _k, &Bls[bb][4096 + w * 512]);           \
  } while (0)

#define COMPUTE(bb) do {                                                       \
    short8 af[8], bf[4];                                                       \
    _Pragma("unroll")                                                          \
    for (int m = 0; m < 8; ++m)                                                \
      af[m] = *(const short8*)&Als[bb][(wm * 128 + m * 16 + frow) * 32 +       \
                                       (fk ^ rswz)];                           \
    _Pragma("unroll")                                                          \
    for (int n = 0; n < 4; ++n)                                                \
      bf[n] = *(const short8*)&Bls[bb][(wn * 64 + n * 16 + frow) * 32 +        \
                                       (fk ^ rswz)];                           \
    __builtin_amdgcn_s_setprio(1);                                             \
    _Pragma("unroll")                                                          \
    for (int m = 0; m < 8; ++m)                                                \
      _Pragma("unroll")                                                        \
      for (int n = 0; n < 4; ++n)                                              \
        acc[m][n] = __builtin_amdgcn_mfma_f32_16x16x32_bf16(af[m], bf[n],      \
                                                        acc[m][n], 0, 0, 0);   \
    __builtin_amdgcn_s_setprio(0);                                             \
  } while (0)

  // ITER: stage chunk K+2 into buf (CUR+2)%3, wait own loads for buf CUR
  // (counted: 2 stages = 8 loads remain in flight), barrier, compute.
#define ITER(K, CUR, VM) do {                                                  \
    if ((K) < 30) STAGE(((CUR) + 2) % 3, (K) + 2);                             \
    asm volatile("s_waitcnt vmcnt(" #VM ")" ::: "memory");                     \
    __builtin_amdgcn_s_barrier();                                              \
    COMPUTE(CUR);                                                              \
    __builtin_amdgcn_s_barrier();                                              \
  } while (0)

  STAGE(0, 0);
  STAGE(1, 1);
  for (int kb = 0; kb < 30; kb += 3) {   // D/32 = 32 chunks total
    ITER(kb + 0, 0, 8);
    ITER(kb + 1, 1, 8);
    ITER(kb + 2, 2, 8);
  }
  ITER(30, 0, 4);
  ITER(31, 1, 0);
#undef STAGE
#undef COMPUTE
#undef ITER

  // Epilogue. C/D mapping: col = lane&15, row = (lane>>4)*4 + reg.
  // For fixed (m,r): 16 lanes sharing (l>>4) hold the same output row,
  // cols col0 + n*16 + (l&15) -> shfl_xor {1,2,4,8} row-reduces.
  const int row0 = bm * 256 + wm * 128;
  const int col0 = bn * 256 + wn * 64;
  const int tile = bn * 4 + wn;          // 16 blocks x 4 = 64 tiles of 64 cols
  int lc[4];
  #pragma unroll
  for (int n = 0; n < 4; ++n) lc[n] = lbl[col0 + n * 16 + (l & 15)];

  #pragma unroll
  for (int m = 0; m < 8; ++m) {
    #pragma unroll
    for (int r = 0; r < 4; ++r) {
      const int grow = row0 + m * 16 + (l >> 4) * 4 + r;
      const int lr = lbl[grow];
      const size_t base = (size_t)grow * N + col0 + (l & 15);
      float s = 0.0f, p = 0.0f;
      #pragma unroll
      for (int n = 0; n < 4; ++n) {
        const float v = acc[m][n][r];
        sim[base + n * 16] = v;
        s += exp2f(v * LOG2E_X20);
        p += (lc[n] == lr) ? v : 0.0f;
      }
      #pragma unroll
      for (int off = 1; off < 16; off <<= 1) {
        s += __shfl_xor(s, off);
        p += __shfl_xor(p, off);
      }
      if ((l & 15) == 0) {
        float* pp = &part[(size_t)grow * 128 + tile * 2];
        pp[0] = s;
        pp[1] = p;
      }
    }
  }
}

// ---------------------------------------------------------------------------
// Kernel 4: finalize. 16 blocks x 256 thr; thread t of block b owns row i.
// ---------------------------------------------------------------------------
__global__ __launch_bounds__(256) void finalize_k(
    const float* __restrict__ part, const int* __restrict__ lbl,
    float* loss_slot) {
  __shared__ int hist[64];
  __shared__ float redl[4];
  const int t = threadIdx.x;
  const int i = blockIdx.x * 256 + t;

  if (t < 64) hist[t] = 0;
  __syncthreads();
  for (int j = t; j < N; j += 256) atomicAdd(&hist[lbl[j] & 63], 1);
  __syncthreads();

  const float* pr = part + (size_t)i * 128;
  float sexp = 0.0f, psum = 0.0f;
  #pragma unroll
  for (int tt = 0; tt < 64; ++tt) {
    sexp += pr[tt * 2];
    psum += pr[tt * 2 + 1];
  }
  const float cnt = (float)hist[lbl[i] & 63];
  const float row = TEMP_INV * psum / cnt - logf(sexp);
  float contrib = -row * (1.0f / (float)N);

  #pragma unroll
  for (int off = 32; off > 0; off >>= 1) contrib += __shfl_xor(contrib, off);
  if ((t & 63) == 0) redl[t >> 6] = contrib;
  __syncthreads();
  if (t == 0) atomicAdd(loss_slot, redl[0] + redl[1] + redl[2] + redl[3]);
}

// ---------------------------------------------------------------------------
extern "C" void kernel_launch(void* const* d_in, const int* in_sizes, int n_in,
                              void* d_out, int out_size, void* d_ws, size_t ws_size,
                              hipStream_t stream) {
  const float* c  = (const float*)d_in[0];
  const float* ch = (const float*)d_in[1];
  const int* lbl  = (const int*)d_in[2];

  float* out = (float*)d_out;
  float* sim = out;                            // [N*N]
  float* loss_slot = out + (size_t)N * N;      // [1]
  float* ytrue = out + (size_t)N * N + 1;      // [N*N] (only 4B-aligned!)

  unsigned short* cnb  = (unsigned short*)d_ws;            // bf16 cn  [N][D]
  unsigned short* chnb = cnb + (size_t)N * D;              // bf16 chn [N][D]
  float* part = (float*)(chnb + (size_t)N * D);            // [N][64][2] = 2 MB

  normalize_k<<<2 * N, 256, 0, stream>>>(c, ch, cnb, chnb, loss_slot);
  ytrue_k<<<N * N / 1024, 256, 0, stream>>>(lbl, ytrue);
  dim3 g(N / 256, N / 256);
  gemm_k<<<g, 512, 0, stream>>>(cnb, chnb, lbl, sim, part);
  finalize_k<<<N / 256, 256, 0, stream>>>(part, lbl, loss_slot);
}

// Round 12
// 204.736 us; speedup vs baseline: 1.1262x; 1.0453x over previous
//
#include <hip/hip_runtime.h>
#include <hip/hip_bf16.h>

typedef __attribute__((ext_vector_type(8))) short short8;
typedef __attribute__((ext_vector_type(4))) float f32x4;

static constexpr int N = 4096;
static constexpr int D = 1024;
#define TEMP_INV 20.0f
#define LOG2E_X20 28.8539008178f   // 20 * log2(e); exp(20x) == exp2(x * this)

#define GLD_LDS16(gp, lp) __builtin_amdgcn_global_load_lds(                      \
    (const __attribute__((address_space(1))) void*)(gp),                         \
    (__attribute__((address_space(3))) void*)(lp), 16, 0, 0)

// ---------------------------------------------------------------------------
// Kernel 1: row-normalize c and ch -> bf16 workspace; zero the loss slot.
// ---------------------------------------------------------------------------
__global__ __launch_bounds__(256) void normalize_k(
    const float* __restrict__ c, const float* __restrict__ ch,
    unsigned short* __restrict__ cnb, unsigned short* __restrict__ chnb,
    float* __restrict__ loss_slot) {
  const int r = blockIdx.x;   // 0..2N-1
  const int t = threadIdx.x;  // 0..255
  if (r == 0 && t == 0) *loss_slot = 0.0f;

  const float* src = (r < N) ? (c + (size_t)r * D) : (ch + (size_t)(r - N) * D);
  unsigned short* dst = (r < N) ? (cnb + (size_t)r * D) : (chnb + (size_t)(r - N) * D);

  float4 v = ((const float4*)src)[t];
  float ss = v.x * v.x + v.y * v.y + v.z * v.z + v.w * v.w;
  #pragma unroll
  for (int off = 32; off > 0; off >>= 1) ss += __shfl_xor(ss, off);
  __shared__ float red[4];
  if ((t & 63) == 0) red[t >> 6] = ss;
  __syncthreads();
  float tot = red[0] + red[1] + red[2] + red[3];
  float sc = 1.0f / fmaxf(sqrtf(tot), 1e-8f);

  __hip_bfloat16 b0 = __float2bfloat16(v.x * sc);
  __hip_bfloat16 b1 = __float2bfloat16(v.y * sc);
  __hip_bfloat16 b2 = __float2bfloat16(v.z * sc);
  __hip_bfloat16 b3 = __float2bfloat16(v.w * sc);
  ushort4 o;
  o.x = *(unsigned short*)&b0;
  o.y = *(unsigned short*)&b1;
  o.z = *(unsigned short*)&b2;
  o.w = *(unsigned short*)&b3;
  ((ushort4*)dst)[t] = o;
}

// ---------------------------------------------------------------------------
// Kernel 2: y_true[i][j] = (label_i == label_j).
// yt = out + N*N + 1 is only 4-byte aligned -> scalar dword stores only.
// ---------------------------------------------------------------------------
__global__ __launch_bounds__(256) void ytrue_k(
    const int* __restrict__ lbl, float* __restrict__ yt) {
  const size_t base = (size_t)blockIdx.x * 1024;
  const int row = (int)(base >> 12);
  const int lr = lbl[row];
  #pragma unroll
  for (int q = 0; q < 4; ++q) {
    const size_t e = base + q * 256 + threadIdx.x;
    const int col = (int)(e & 4095);
    yt[e] = (lbl[col] == lr) ? 1.0f : 0.0f;
  }
}

// ---------------------------------------------------------------------------
// Kernel 3: NT bf16 MFMA GEMM, 256x256 tile, BK=32, 8 waves (2M x 4N),
// QUAD-buffered LDS (4 x 16 KB/op = 128 KB), stage-2-ahead, counted vmcnt
// (never 0 mid-loop), ONE barrier per iter (NB-S>=2 makes the closing
// barrier unnecessary: buf k%4 is re-staged at iter k+2, and 1-barrier/iter
// bounds wave skew to <1 iter -> no reader/writer overlap). This enables
// wave-slip: fast waves stage ahead while slow waves finish MFMA.
// T2 swizzle: 16B-slot involution slot^=(row>>1)&3 on the GLOBAL SOURCE
// (LDS dest linear, required by global_load_lds) and on the ds_read col.
// T5 setprio around MFMA. T1 XCD-aware block swizzle (256 blocks = 8 x 32).
// Writes sim and per-wave per-row loss partials:
//   part[row][tile] = { s = sum_cols exp(20*v), p = sum_cols mask*v },
// tile = bn*4 + wn (64 col-chunks of 64). No max subtraction: |v|<=1.
// ---------------------------------------------------------------------------
__global__ __launch_bounds__(512) void gemm_k(
    const unsigned short* __restrict__ A,  // cn  bf16 [N][D]
    const unsigned short* __restrict__ B,  // chn bf16 [N][D]
    const int* __restrict__ lbl,
    float* __restrict__ sim, float* __restrict__ part) {
  __shared__ __align__(16) unsigned short Als[4][256 * 32];  // 16 KB x4
  __shared__ __align__(16) unsigned short Bls[4][256 * 32];  // 16 KB x4

  const int t = threadIdx.x;             // 0..511
  const int w = t >> 6, l = t & 63;      // 8 waves
  // T1: XCD-aware swizzle. 256 blocks, 8 XCDs, cpx=32 (bijective).
  const int bid = blockIdx.x;
  const int swz = (bid & 7) * 32 + (bid >> 3);
  const int bm = swz >> 4, bn = swz & 15;
  const int wm = w >> 2, wn = w & 3;     // 2M x 4N

  f32x4 acc[8][4] = {};

  // staging (per op, per stage): 256x32 bf16 = 16 KB = 1024 chunks of 16 B,
  // 2 chunks/thread. chunk c = q*512 + t: row = q*128 + (t>>2), slot = t&3.
  // Source slot pre-swizzled: slot ^ ((row>>1)&3) = (t&3)^((t>>3)&3).
  // LDS dest linear: elem c*8 = q*4096 + w*512 (+ lane*8 by HW).
  const int srow = t >> 2;
  const int sslot = (t & 3) ^ ((t >> 3) & 3);
  const unsigned short* gaS = A + (size_t)(bm * 256 + srow) * D + sslot * 8;
  const unsigned short* gbS = B + (size_t)(bn * 256 + srow) * D + sslot * 8;

  const int frow = (l & 15);
  const int fk = (l >> 4) * 8;
  const int rswz = ((frow >> 1) & 3) << 3;   // read-side swizzle (elems)

#define STAGE(bb, ks) do {                                                     \
    const int _k = (ks) * 32;                                                  \
    GLD_LDS16(gaS + _k, &Als[bb][w * 512]);                                    \
    GLD_LDS16(gaS + (size_t)128 * D + _k, &Als[bb][4096 + w * 512]);           \
    GLD_LDS16(gbS + _k, &Bls[bb][w * 512]);                                    \
    GLD_LDS16(gbS + (size_t)128 * D + _k, &Bls[bb][4096 + w * 512]);           \
  } while (0)

#define COMPUTE(bb) do {                                                       \
    short8 af[8], bf[4];                                                       \
    _Pragma("unroll")                                                          \
    for (int m = 0; m < 8; ++m)                                                \
      af[m] = *(const short8*)&Als[bb][(wm * 128 + m * 16 + frow) * 32 +       \
                                       (fk ^ rswz)];                           \
    _Pragma("unroll")                                                          \
    for (int n = 0; n < 4; ++n)                                                \
      bf[n] = *(const short8*)&Bls[bb][(wn * 64 + n * 16 + frow) * 32 +        \
                                       (fk ^ rswz)];                           \
    __builtin_amdgcn_s_setprio(1);                                             \
    _Pragma("unroll")                                                          \
    for (int m = 0; m < 8; ++m)                                                \
      _Pragma("unroll")                                                        \
      for (int n = 0; n < 4; ++n)                                              \
        acc[m][n] = __builtin_amdgcn_mfma_f32_16x16x32_bf16(af[m], bf[n],      \
                                                        acc[m][n], 0, 0, 0);   \
    __builtin_amdgcn_s_setprio(0);                                             \
  } while (0)

  // ITER: stage chunk K+2 into buf (K+2)%4; wait own loads so chunk K is
  // done (2 stages = 8 loads may remain in flight); barrier publishes all
  // waves' chunk-K loads; compute. NO closing barrier (see header comment).
#define ITER(K, CUR, VM) do {                                                  \
    if ((K) < 30) STAGE(((CUR) + 2) & 3, (K) + 2);                             \
    asm volatile("s_waitcnt vmcnt(" #VM ")" ::: "memory");                     \
    __builtin_amdgcn_s_barrier();                                              \
    COMPUTE(CUR);                                                              \
  } while (0)

  STAGE(0, 0);
  STAGE(1, 1);
  for (int kb = 0; kb < 28; kb += 4) {   // D/32 = 32 chunks total
    ITER(kb + 0, 0, 8);
    ITER(kb + 1, 1, 8);
    ITER(kb + 2, 2, 8);
    ITER(kb + 3, 3, 8);
  }
  ITER(28, 0, 8);
  ITER(29, 1, 8);
  ITER(30, 2, 4);
  ITER(31, 3, 0);
#undef STAGE
#undef COMPUTE
#undef ITER

  // Epilogue. C/D mapping: col = lane&15, row = (lane>>4)*4 + reg.
  // For fixed (m,r): 16 lanes sharing (l>>4) hold the same output row,
  // cols col0 + n*16 + (l&15) -> shfl_xor {1,2,4,8} row-reduces.
  const int row0 = bm * 256 + wm * 128;
  const int col0 = bn * 256 + wn * 64;
  const int tile = bn * 4 + wn;          // 16 blocks x 4 = 64 tiles of 64 cols
  int lc[4];
  #pragma unroll
  for (int n = 0; n < 4; ++n) lc[n] = lbl[col0 + n * 16 + (l & 15)];

  #pragma unroll
  for (int m = 0; m < 8; ++m) {
    #pragma unroll
    for (int r = 0; r < 4; ++r) {
      const int grow = row0 + m * 16 + (l >> 4) * 4 + r;
      const int lr = lbl[grow];
      const size_t base = (size_t)grow * N + col0 + (l & 15);
      float s = 0.0f, p = 0.0f;
      #pragma unroll
      for (int n = 0; n < 4; ++n) {
        const float v = acc[m][n][r];
        sim[base + n * 16] = v;
        s += exp2f(v * LOG2E_X20);
        p += (lc[n] == lr) ? v : 0.0f;
      }
      #pragma unroll
      for (int off = 1; off < 16; off <<= 1) {
        s += __shfl_xor(s, off);
        p += __shfl_xor(p, off);
      }
      if ((l & 15) == 0) {
        float* pp = &part[(size_t)grow * 128 + tile * 2];
        pp[0] = s;
        pp[1] = p;
      }
    }
  }
}

// ---------------------------------------------------------------------------
// Kernel 4: finalize. 16 blocks x 256 thr; thread t of block b owns row i.
// ---------------------------------------------------------------------------
__global__ __launch_bounds__(256) void finalize_k(
    const float* __restrict__ part, const int* __restrict__ lbl,
    float* loss_slot) {
  __shared__ int hist[64];
  __shared__ float redl[4];
  const int t = threadIdx.x;
  const int i = blockIdx.x * 256 + t;

  if (t < 64) hist[t] = 0;
  __syncthreads();
  for (int j = t; j < N; j += 256) atomicAdd(&hist[lbl[j] & 63], 1);
  __syncthreads();

  const float* pr = part + (size_t)i * 128;
  float sexp = 0.0f, psum = 0.0f;
  #pragma unroll
  for (int tt = 0; tt < 64; ++tt) {
    sexp += pr[tt * 2];
    psum += pr[tt * 2 + 1];
  }
  const float cnt = (float)hist[lbl[i] & 63];
  const float row = TEMP_INV * psum / cnt - logf(sexp);
  float contrib = -row * (1.0f / (float)N);

  #pragma unroll
  for (int off = 32; off > 0; off >>= 1) contrib += __shfl_xor(contrib, off);
  if ((t & 63) == 0) redl[t >> 6] = contrib;
  __syncthreads();
  if (t == 0) atomicAdd(loss_slot, redl[0] + redl[1] + redl[2] + redl[3]);
}

// ---------------------------------------------------------------------------
extern "C" void kernel_launch(void* const* d_in, const int* in_sizes, int n_in,
                              void* d_out, int out_size, void* d_ws, size_t ws_size,
                              hipStream_t stream) {
  const float* c  = (const float*)d_in[0];
  const float* ch = (const float*)d_in[1];
  const int* lbl  = (const int*)d_in[2];

  float* out = (float*)d_out;
  float* sim = out;                            // [N*N]
  float* loss_slot = out + (size_t)N * N;      // [1]
  float* ytrue = out + (size_t)N * N + 1;      // [N*N] (only 4B-aligned!)

  unsigned short* cnb  = (unsigned short*)d_ws;            // bf16 cn  [N][D]
  unsigned short* chnb = cnb + (size_t)N * D;              // bf16 chn [N][D]
  float* part = (float*)(chnb + (size_t)N * D);            // [N][64][2] = 2 MB

  normalize_k<<<2 * N, 256, 0, stream>>>(c, ch, cnb, chnb, loss_slot);
  ytrue_k<<<N * N / 1024, 256, 0, stream>>>(lbl, ytrue);
  gemm_k<<<256, 512, 0, stream>>>(cnb, chnb, lbl, sim, part);
  finalize_k<<<N / 256, 256, 0, stream>>>(part, lbl, loss_slot);
}